// Round 2
// baseline (123.232 us; speedup 1.0000x reference)
//
#include <hip/hip_runtime.h>
#include <hip/hip_cooperative_groups.h>

namespace cg = cooperative_groups;

#define KK 16
#define NPIX 16384   // 128*128

// ws layout (no zero-init required — kernel initializes acc/cnt before grid sync):
//   [0    .. 1023]  : int    maxpart[256]  per-block D2 max, index = b*128 + k*8 + rg
//   [1024 .. 1027]  : float  acc           loss accumulator
//   [1028 .. 1031]  : uint   cnt           ticket counter
//   [4096 .. +1MB]  : u16    d2[2*16*16384] squared EDT per (b,k,pixel), <= 40000

// packed u16 pair: per-element min of (a,b), then square (nd<=200 -> nd^2<=40000 fits u16)
__device__ __forceinline__ unsigned pk_min_sq(unsigned a, unsigned b) {
    const unsigned lo = min(a & 0xffffu, b & 0xffffu);
    const unsigned hi = min(a >> 16, b >> 16);
    return (lo * lo) | ((hi * hi) << 16);
}

__global__ __launch_bounds__(256) void fused_kernel(const int* __restrict__ mask,
                                                    const float* __restrict__ pred,
                                                    const float* __restrict__ ign,
                                                    int* __restrict__ maxpart,
                                                    float* __restrict__ acc,
                                                    unsigned int* __restrict__ cnt,
                                                    unsigned short* __restrict__ d2,
                                                    float* __restrict__ out) {
    __shared__ alignas(16) unsigned char  nuc[NPIX];      // 16 KB
    __shared__ alignas(16) unsigned short sdn[NPIX];      // 32 KB: down-dist, then nd^2 (G2)
    __shared__ alignas(16) unsigned short sup[NPIX];      // 32 KB: up-dist
    __shared__ int   wmax[4];
    __shared__ float msq[KK];
    __shared__ float wred[4];

    const int bid = blockIdx.x;       // 0..255
    const int t   = threadIdx.x;      // 0..255
    const int b1  = bid >> 7;         // 0..1
    const int k1  = (bid >> 3) & 15;  // 0..15
    const int rg  = bid & 7;          // 0..7

    // init accumulators BEFORE the grid barrier (sync release/acquire = visibility)
    if (bid == 0 && t == 0) { *acc = 0.0f; *cnt = 0u; }

    // ================= EDT phase: this block owns (b1, k1, row-group rg) ==========

    // ---- stage nuclei bytes (int4 mask loads) ----
    const int label1 = k1 + 1;
    const int4* m4 = (const int4*)(mask + b1 * NPIX);
    #pragma unroll
    for (int it = 0; it < 16; ++it) {
        const int idx = t + 256 * it;          // 0..4095
        const int4 v = m4[idx];
        uchar4 u;
        u.x = (v.x == label1); u.y = (v.y == label1);
        u.z = (v.z == label1); u.w = (v.w == label1);
        *(uchar4*)&nuc[idx * 4] = u;
    }
    __syncthreads();

    // ---- concurrent down/up 1D column scans (sentinel 200) ----
    if (t < 128) {
        const int j = t;
        int dist = 200;
        #pragma unroll 4
        for (int i = 0; i < 128; ++i) {
            dist = nuc[i * 128 + j] ? min(dist + 1, 200) : 0;
            sdn[i * 128 + j] = (unsigned short)dist;
        }
    } else {
        const int j = t - 128;
        int dist = 200;
        #pragma unroll 4
        for (int i = 127; i >= 0; --i) {
            dist = nuc[i * 128 + j] ? min(dist + 1, 200) : 0;
            sup[i * 128 + j] = (unsigned short)dist;
        }
    }
    __syncthreads();

    // ---- combine: G2 = min(down,up)^2, vectorized 8 u16 per iteration ----
    {
        const uint4* a4 = (const uint4*)sdn;
        const uint4* b4 = (const uint4*)sup;
        uint4*       o4 = (uint4*)sdn;
        #pragma unroll
        for (int g = 0; g < 8; ++g) {
            const int i4 = t + 256 * g;        // 0..2047
            const uint4 a = a4[i4];
            const uint4 b = b4[i4];
            uint4 r;
            r.x = pk_min_sq(a.x, b.x);
            r.y = pk_min_sq(a.y, b.y);
            r.z = pk_min_sq(a.z, b.z);
            r.w = pk_min_sq(a.w, b.w);
            o4[i4] = r;
        }
    }
    __syncthreads();

    // ---- windowed row pass: D2[j] = min_jp( G2[jp] + (j-jp)^2 ) ----
    // Exact: after evaluating jp in [c0-e, c0+7+e], every unevaluated candidate
    // contributes >= (e+1)^2; stop once that can't beat any of the lane's 8 bests.
    const int row = rg * 16 + (t >> 4);
    const int c0  = (t & 15) * 8;
    const unsigned short* grow = &sdn[row * 128];

    const uint4 gv = *(const uint4*)(grow + c0);
    int g[8];
    g[0] = (int)(gv.x & 0xffffu); g[1] = (int)(gv.x >> 16);
    g[2] = (int)(gv.y & 0xffffu); g[3] = (int)(gv.y >> 16);
    g[4] = (int)(gv.z & 0xffffu); g[5] = (int)(gv.z >> 16);
    g[6] = (int)(gv.w & 0xffffu); g[7] = (int)(gv.w >> 16);

    int best[8];
    #pragma unroll
    for (int u = 0; u < 8; ++u) best[u] = 0x7fffffff;
    #pragma unroll
    for (int w = 0; w < 8; ++w) {
        #pragma unroll
        for (int u = 0; u < 8; ++u) {
            const int dj = u - w;                 // compile-time constant
            best[u] = min(best[u], g[w] + dj * dj);
        }
    }
    int mb = 0;
    #pragma unroll
    for (int u = 0; u < 8; ++u) mb = max(mb, best[u]);

    for (int e = 0; e < 128; ++e) {
        if (!__any((e + 1) * (e + 1) < mb)) break;
        const int jl = c0 - 1 - e;
        const int jr = c0 + 8 + e;
        if (jl >= 0) {
            const int gl = (int)grow[jl];
            #pragma unroll
            for (int u = 0; u < 8; ++u) {
                const int dj = u + 1 + e;         // (c0+u) - jl
                best[u] = min(best[u], gl + dj * dj);
            }
        }
        if (jr < 128) {
            const int gr = (int)grow[jr];
            #pragma unroll
            for (int u = 0; u < 8; ++u) {
                const int dj = 8 + e - u;         // jr - (c0+u)
                best[u] = min(best[u], gr + dj * dj);
            }
        }
        mb = 0;
        #pragma unroll
        for (int u = 0; u < 8; ++u) mb = max(mb, best[u]);
    }

    // pack 8 u16 D2 values -> one 16B store
    uint4 w;
    w.x = (unsigned)best[0] | ((unsigned)best[1] << 16);
    w.y = (unsigned)best[2] | ((unsigned)best[3] << 16);
    w.z = (unsigned)best[4] | ((unsigned)best[5] << 16);
    w.w = (unsigned)best[6] | ((unsigned)best[7] << 16);
    *(uint4*)(d2 + (b1 * KK + k1) * NPIX + row * 128 + c0) = w;

    // block max of D2 (mb already = this lane's max over its 8 columns)
    int bm = mb;
    #pragma unroll
    for (int off = 32; off; off >>= 1) bm = max(bm, __shfl_down(bm, off, 64));
    if ((t & 63) == 0) wmax[t >> 6] = bm;
    __syncthreads();
    if (t == 0)
        maxpart[bid] = max(max(wmax[0], wmax[1]), max(wmax[2], wmax[3]));

    // ================= grid-wide barrier =================
    __threadfence();
    cg::this_grid().sync();

    // ================= gt + loss phase =================
    // 256 blocks x 256 threads over 32768 pixels x 2 channel-halves.
    // t&127 = pixel within block's 128-pixel chunk; t>>7 selects channels 0-3 / 4-7.
    const int tp  = t & 127;
    const int ch0 = (t >> 7) * 4;
    const int p   = bid * 128 + tp;       // global pixel 0..32767
    const int pp  = p & (NPIX - 1);       // pixel within image; image index = b1

    // msq[k] = sqrt(max D2) for this b (reduce the 8 row-group partials)
    if (t < KK) {
        const int base = b1 * 128 + t * 8;
        int mt = 0;
        #pragma unroll
        for (int r = 0; r < 8; ++r) mt = max(mt, maxpart[base + r]);
        msq[t] = __fsqrt_rn((float)mt);
    }
    __syncthreads();

    const int label = mask[p];
    int cbin = -1;                        // which gt channel is 1 (none if bg)
    if (label > 0) {
        const int k = label - 1;
        const float d  = __fsqrt_rn((float)d2[(b1 * KK + k) * NPIX + pp]);  // D2>=1
        float dn = __fdiv_rn(d, msq[k]);  // msq >= 1 since maxD2 >= D2 >= 1
        if (dn < 0.5f) dn = 0.0f;
        if (dn > 0.7f) dn = 1.0f;
        const float ddd[8] = {0.83f, 0.68f, 0.54f, 0.41f, 0.29f, 0.18f, 0.09f, 0.0f};
        #pragma unroll
        for (int c = 0; c < 8; ++c) {
            if (cbin < 0 && dn >= ddd[c]) cbin = c;
        }
    }

    float lsum = 0.0f;
    #pragma unroll
    for (int cc = 0; cc < 4; ++cc) {
        const int c = ch0 + cc;
        const float gt = (c == cbin) ? 1.0f : 0.0f;
        out[1 + (b1 * 8 + c) * NPIX + pp] = gt;
        const float diff = pred[(b1 * 8 + c) * NPIX + pp] - gt;
        const float ad = fabsf(diff);
        lsum += (ad < 1.0f) ? 0.5f * diff * diff : (ad - 0.5f);
    }
    float contrib = lsum * 0.125f * ign[p];

    #pragma unroll
    for (int off = 32; off; off >>= 1) contrib += __shfl_down(contrib, off, 64);
    if ((t & 63) == 0) wred[t >> 6] = contrib;
    __syncthreads();

    if (t == 0) {
        atomicAdd(acc, (wred[0] + wred[1]) + (wred[2] + wred[3]));
        __threadfence();
        const unsigned int old = atomicAdd(cnt, 1u);
        if (old == 255u) {                        // last block: all adds visible
            const float total = atomicAdd(acc, 0.0f);
            out[0] = total * (1.0f / 32768.0f);
        }
    }
}

extern "C" void kernel_launch(void* const* d_in, const int* in_sizes, int n_in,
                              void* d_out, int out_size, void* d_ws, size_t ws_size,
                              hipStream_t stream) {
    const int*   mask = (const int*)d_in[1];
    const float* pred = (const float*)d_in[0];
    const float* ign  = (const float*)d_in[2];
    float* out = (float*)d_out;

    int*            maxpart = (int*)d_ws;
    float*          acc     = (float*)((char*)d_ws + 1024);
    unsigned int*   cnt     = (unsigned int*)((char*)d_ws + 1028);
    unsigned short* d2      = (unsigned short*)((char*)d_ws + 4096);

    void* args[] = {(void*)&mask, (void*)&pred, (void*)&ign, (void*)&maxpart,
                    (void*)&acc, (void*)&cnt, (void*)&d2, (void*)&out};
    hipLaunchCooperativeKernel((const void*)fused_kernel, dim3(256), dim3(256),
                               args, 0, stream);
}

// Round 3
// 105.138 us; speedup vs baseline: 1.1721x; 1.1721x over previous
//
#include <hip/hip_runtime.h>

#define KK 16
#define NPIX 16384   // 128*128

#define MAGA 0x13579BDFu
#define MAGB 0xECA86420u
#define SCOPE __HIP_MEMORY_SCOPE_AGENT

// ws layout (poison-safe: all counters behind dual-magic init flags, self-resetting):
//   [0    .. 1023]  : int    maxpart[256]  per-block D2 max, index = b*128 + k*8 + rg
//   [1024]          : float  acc           loss accumulator (self-resets to 0)
//   [1028]          : uint   cnt2          phase-2 ticket   (self-resets to 0)
//   [1032]          : uint   arrive        barrier arrivals (self-resets to 0)
//   [1036]          : uint   release       barrier epoch    (monotonic)
//   [1040]          : uint   flagA, [1044] flagB   init-done magics
//   [4096 .. +1MB]  : u16    d2[2*16*16384] squared EDT per (b,k,pixel), <= 40000

// packed u16 pair: per-element min of (a,b), then square (nd<=200 -> nd^2<=40000 fits u16)
__device__ __forceinline__ unsigned pk_min_sq(unsigned a, unsigned b) {
    const unsigned lo = min(a & 0xffffu, b & 0xffffu);
    const unsigned hi = min(a >> 16, b >> 16);
    return (lo * lo) | ((hi * hi) << 16);
}

__global__ __launch_bounds__(256) void fused_kernel(const int* __restrict__ mask,
                                                    const float* __restrict__ pred,
                                                    const float* __restrict__ ign,
                                                    int* __restrict__ maxpart,
                                                    float* __restrict__ acc,
                                                    unsigned int* __restrict__ cnt2,
                                                    unsigned int* __restrict__ arrive,
                                                    unsigned int* __restrict__ release,
                                                    unsigned int* __restrict__ flagA,
                                                    unsigned int* __restrict__ flagB,
                                                    unsigned short* __restrict__ d2,
                                                    float* __restrict__ out) {
    __shared__ alignas(16) unsigned char  nuc[NPIX];      // 16 KB
    __shared__ alignas(16) unsigned short sdn[NPIX];      // 32 KB: down-dist, then nd^2 (G2)
    __shared__ alignas(16) unsigned short sup[NPIX];      // 32 KB: up-dist
    __shared__ int   wmax[4];
    __shared__ float msq[KK];
    __shared__ float wred[4];

    const int bid = blockIdx.x;       // 0..255
    const int t   = threadIdx.x;      // 0..255
    const int b1  = bid >> 7;         // 0..1
    const int k1  = (bid >> 3) & 15;  // 0..15
    const int rg  = bid & 7;          // 0..7

    // ---- one-time counter init after workspace poison (dual-magic gate) ----
    // A single repeated poison pattern cannot equal BOTH magics, so a poisoned
    // workspace always re-inits; an un-poisoned replay skips (counters self-reset).
    if (bid == 0 && t == 0) {
        if (__hip_atomic_load(flagA, __ATOMIC_RELAXED, SCOPE) != MAGA ||
            __hip_atomic_load(flagB, __ATOMIC_RELAXED, SCOPE) != MAGB) {
            __hip_atomic_store(acc,     0.0f, __ATOMIC_RELAXED, SCOPE);
            __hip_atomic_store(cnt2,    0u,   __ATOMIC_RELAXED, SCOPE);
            __hip_atomic_store(arrive,  0u,   __ATOMIC_RELAXED, SCOPE);
            __hip_atomic_store(release, 0u,   __ATOMIC_RELAXED, SCOPE);
            __hip_atomic_store(flagA, MAGA, __ATOMIC_RELEASE, SCOPE);
            __hip_atomic_store(flagB, MAGB, __ATOMIC_RELEASE, SCOPE);
        }
    }

    // ================= EDT phase: this block owns (b1, k1, row-group rg) ==========

    // ---- stage nuclei bytes (int4 mask loads) ----
    const int label1 = k1 + 1;
    const int4* m4 = (const int4*)(mask + b1 * NPIX);
    #pragma unroll
    for (int it = 0; it < 16; ++it) {
        const int idx = t + 256 * it;          // 0..4095
        const int4 v = m4[idx];
        uchar4 u;
        u.x = (v.x == label1); u.y = (v.y == label1);
        u.z = (v.z == label1); u.w = (v.w == label1);
        *(uchar4*)&nuc[idx * 4] = u;
    }
    __syncthreads();

    // ---- concurrent down/up 1D column scans (sentinel 200) ----
    if (t < 128) {
        const int j = t;
        int dist = 200;
        #pragma unroll 4
        for (int i = 0; i < 128; ++i) {
            dist = nuc[i * 128 + j] ? min(dist + 1, 200) : 0;
            sdn[i * 128 + j] = (unsigned short)dist;
        }
    } else {
        const int j = t - 128;
        int dist = 200;
        #pragma unroll 4
        for (int i = 127; i >= 0; --i) {
            dist = nuc[i * 128 + j] ? min(dist + 1, 200) : 0;
            sup[i * 128 + j] = (unsigned short)dist;
        }
    }
    __syncthreads();

    // ---- combine: G2 = min(down,up)^2, vectorized 8 u16 per iteration ----
    {
        const uint4* a4 = (const uint4*)sdn;
        const uint4* b4 = (const uint4*)sup;
        uint4*       o4 = (uint4*)sdn;
        #pragma unroll
        for (int g = 0; g < 8; ++g) {
            const int i4 = t + 256 * g;        // 0..2047
            const uint4 a = a4[i4];
            const uint4 b = b4[i4];
            uint4 r;
            r.x = pk_min_sq(a.x, b.x);
            r.y = pk_min_sq(a.y, b.y);
            r.z = pk_min_sq(a.z, b.z);
            r.w = pk_min_sq(a.w, b.w);
            o4[i4] = r;
        }
    }
    __syncthreads();

    // ---- windowed row pass: D2[j] = min_jp( G2[jp] + (j-jp)^2 ) ----
    const int row = rg * 16 + (t >> 4);
    const int c0  = (t & 15) * 8;
    const unsigned short* grow = &sdn[row * 128];

    const uint4 gv = *(const uint4*)(grow + c0);
    int g[8];
    g[0] = (int)(gv.x & 0xffffu); g[1] = (int)(gv.x >> 16);
    g[2] = (int)(gv.y & 0xffffu); g[3] = (int)(gv.y >> 16);
    g[4] = (int)(gv.z & 0xffffu); g[5] = (int)(gv.z >> 16);
    g[6] = (int)(gv.w & 0xffffu); g[7] = (int)(gv.w >> 16);

    int best[8];
    #pragma unroll
    for (int u = 0; u < 8; ++u) best[u] = 0x7fffffff;
    #pragma unroll
    for (int w = 0; w < 8; ++w) {
        #pragma unroll
        for (int u = 0; u < 8; ++u) {
            const int dj = u - w;                 // compile-time constant
            best[u] = min(best[u], g[w] + dj * dj);
        }
    }
    int mb = 0;
    #pragma unroll
    for (int u = 0; u < 8; ++u) mb = max(mb, best[u]);

    for (int e = 0; e < 128; ++e) {
        if (!__any((e + 1) * (e + 1) < mb)) break;
        const int jl = c0 - 1 - e;
        const int jr = c0 + 8 + e;
        if (jl >= 0) {
            const int gl = (int)grow[jl];
            #pragma unroll
            for (int u = 0; u < 8; ++u) {
                const int dj = u + 1 + e;         // (c0+u) - jl
                best[u] = min(best[u], gl + dj * dj);
            }
        }
        if (jr < 128) {
            const int gr = (int)grow[jr];
            #pragma unroll
            for (int u = 0; u < 8; ++u) {
                const int dj = 8 + e - u;         // jr - (c0+u)
                best[u] = min(best[u], gr + dj * dj);
            }
        }
        mb = 0;
        #pragma unroll
        for (int u = 0; u < 8; ++u) mb = max(mb, best[u]);
    }

    // pack 8 u16 D2 values -> one 16B store
    uint4 w;
    w.x = (unsigned)best[0] | ((unsigned)best[1] << 16);
    w.y = (unsigned)best[2] | ((unsigned)best[3] << 16);
    w.z = (unsigned)best[4] | ((unsigned)best[5] << 16);
    w.w = (unsigned)best[6] | ((unsigned)best[7] << 16);
    *(uint4*)(d2 + (b1 * KK + k1) * NPIX + row * 128 + c0) = w;

    // block max of D2 (mb already = this lane's max over its 8 columns)
    int bm = mb;
    #pragma unroll
    for (int off = 32; off; off >>= 1) bm = max(bm, __shfl_down(bm, off, 64));
    if ((t & 63) == 0) wmax[t >> 6] = bm;
    __syncthreads();
    if (t == 0)
        maxpart[bid] = max(max(wmax[0], wmax[1]), max(wmax[2], wmax[3]));

    // ---- pre-barrier prefetch of phase-2 pure inputs (latency hides under barrier) ----
    const int tp  = t & 127;
    const int ch0 = (t >> 7) * 4;
    const int p   = bid * 128 + tp;       // global pixel 0..32767
    const int pp  = p & (NPIX - 1);       // pixel within image; image index = b1
    const int label = mask[p];
    const float ig  = ign[p];
    float pr[4];
    #pragma unroll
    for (int cc = 0; cc < 4; ++cc)
        pr[cc] = pred[(b1 * 8 + ch0 + cc) * NPIX + pp];

    // ================= hand-rolled grid barrier (normal launch) =================
    // Safe: LDS 80.5 KB forces exactly 1 block/CU; grid 256 == #CUs => all resident.
    __syncthreads();                       // all block lanes done with d2/maxpart stores
    if (t == 0) {
        // wait for counter init (visible long before EDT finishes; ~0 spins)
        while (__hip_atomic_load(flagA, __ATOMIC_ACQUIRE, SCOPE) != MAGA) { __builtin_amdgcn_s_sleep(1); }
        while (__hip_atomic_load(flagB, __ATOMIC_ACQUIRE, SCOPE) != MAGB) { __builtin_amdgcn_s_sleep(1); }
        __threadfence();                   // release d2/maxpart (device scope)
        const unsigned ep = __hip_atomic_load(release, __ATOMIC_RELAXED, SCOPE);
        const unsigned a  = __hip_atomic_fetch_add(arrive, 1u, __ATOMIC_ACQ_REL, SCOPE);
        if (a == 255u) {                   // last arriver: self-reset + new epoch
            __hip_atomic_store(arrive, 0u, __ATOMIC_RELAXED, SCOPE);
            __hip_atomic_fetch_add(release, 1u, __ATOMIC_ACQ_REL, SCOPE);
        } else {
            while (__hip_atomic_load(release, __ATOMIC_ACQUIRE, SCOPE) == ep)
                __builtin_amdgcn_s_sleep(2);
        }
        __threadfence();                   // acquire: invalidate stale cache lines
    }
    __syncthreads();

    // ================= gt + loss phase =================
    // msq[k] = sqrt(max D2) for this b (reduce the 8 row-group partials)
    if (t < KK) {
        const int base = b1 * 128 + t * 8;
        int mt = 0;
        #pragma unroll
        for (int r = 0; r < 8; ++r) mt = max(mt, maxpart[base + r]);
        msq[t] = __fsqrt_rn((float)mt);
    }
    __syncthreads();

    int cbin = -1;                        // which gt channel is 1 (none if bg)
    if (label > 0) {
        const int k = label - 1;
        const float d  = __fsqrt_rn((float)d2[(b1 * KK + k) * NPIX + pp]);  // D2>=1
        float dn = __fdiv_rn(d, msq[k]);  // msq >= 1 since maxD2 >= D2 >= 1
        if (dn < 0.5f) dn = 0.0f;
        if (dn > 0.7f) dn = 1.0f;
        const float ddd[8] = {0.83f, 0.68f, 0.54f, 0.41f, 0.29f, 0.18f, 0.09f, 0.0f};
        #pragma unroll
        for (int c = 0; c < 8; ++c) {
            if (cbin < 0 && dn >= ddd[c]) cbin = c;
        }
    }

    float lsum = 0.0f;
    #pragma unroll
    for (int cc = 0; cc < 4; ++cc) {
        const int c = ch0 + cc;
        const float gt = (c == cbin) ? 1.0f : 0.0f;
        out[1 + (b1 * 8 + c) * NPIX + pp] = gt;
        const float diff = pr[cc] - gt;
        const float ad = fabsf(diff);
        lsum += (ad < 1.0f) ? 0.5f * diff * diff : (ad - 0.5f);
    }
    float contrib = lsum * 0.125f * ig;

    #pragma unroll
    for (int off = 32; off; off >>= 1) contrib += __shfl_down(contrib, off, 64);
    if ((t & 63) == 0) wred[t >> 6] = contrib;
    __syncthreads();

    if (t == 0) {
        atomicAdd(acc, (wred[0] + wred[1]) + (wred[2] + wred[3]));
        __threadfence();
        const unsigned old = __hip_atomic_fetch_add(cnt2, 1u, __ATOMIC_ACQ_REL, SCOPE);
        if (old == 255u) {                 // last block: all adds visible
            const float total = atomicAdd(acc, 0.0f);
            out[0] = total * (1.0f / 32768.0f);
            // self-reset for replay-without-poison
            __hip_atomic_store(cnt2, 0u,  __ATOMIC_RELAXED, SCOPE);
            __hip_atomic_store(acc, 0.0f, __ATOMIC_RELAXED, SCOPE);
        }
    }
}

extern "C" void kernel_launch(void* const* d_in, const int* in_sizes, int n_in,
                              void* d_out, int out_size, void* d_ws, size_t ws_size,
                              hipStream_t stream) {
    const float* pred = (const float*)d_in[0];
    const int*   mask = (const int*)d_in[1];
    const float* ign  = (const float*)d_in[2];
    float* out = (float*)d_out;

    int*            maxpart = (int*)d_ws;
    float*          acc     = (float*)((char*)d_ws + 1024);
    unsigned int*   cnt2    = (unsigned int*)((char*)d_ws + 1028);
    unsigned int*   arrive  = (unsigned int*)((char*)d_ws + 1032);
    unsigned int*   release = (unsigned int*)((char*)d_ws + 1036);
    unsigned int*   flagA   = (unsigned int*)((char*)d_ws + 1040);
    unsigned int*   flagB   = (unsigned int*)((char*)d_ws + 1044);
    unsigned short* d2      = (unsigned short*)((char*)d_ws + 4096);

    fused_kernel<<<256, 256, 0, stream>>>(mask, pred, ign, maxpart, acc, cnt2,
                                          arrive, release, flagA, flagB, d2, out);
}

// Round 4
// 74.101 us; speedup vs baseline: 1.6630x; 1.4188x over previous
//
#include <hip/hip_runtime.h>

#define KK 16
#define NPIX 16384   // 128*128

// ws layout (no zero-init required — K1 initializes acc/cnt, partials are overwritten):
//   [0    .. 1023]  : int    maxpart[256]  per-block D2 max, index = b*128 + k*8 + rg
//   [1024 .. 1027]  : float  acc           loss accumulator   (K1 inits to 0)
//   [1028 .. 1031]  : uint   cnt           ticket counter     (K1 inits to 0)
//   [4096 .. +1MB]  : u16    d2[2*16*16384] squared EDT per (b,k,pixel), <= 40000

__global__ __launch_bounds__(256) void edt_kernel(const int* __restrict__ mask,
                                                  int* __restrict__ maxpart,
                                                  float* __restrict__ acc,
                                                  unsigned int* __restrict__ cnt,
                                                  unsigned short* __restrict__ d2) {
    __shared__ alignas(16) unsigned short sdn[NPIX];      // 32 KB: down-dist
    __shared__ alignas(16) unsigned short sup[NPIX];      // 32 KB: up-dist
    __shared__ int wmax[4];

    const int bid = blockIdx.x;       // 0..255
    const int t   = threadIdx.x;      // 0..255
    const int b1  = bid >> 7;         // 0..1
    const int k1  = (bid >> 3) & 15;  // 0..15
    const int rg  = bid & 7;          // 0..7

    if (bid == 0 && t == 0) { *acc = 0.0f; *cnt = 0u; }  // init for K2
                                                         // (kernel boundary = visibility)

    // ---- column scans straight from global (row-coalesced; L2-resident) ----
    // Removes the LDS staging pass entirely.
    const int label1 = k1 + 1;
    const int* mb = mask + b1 * NPIX;
    if (t < 128) {
        const int j = t;
        int dist = 200;
        #pragma unroll 8
        for (int i = 0; i < 128; ++i) {
            dist = (mb[i * 128 + j] == label1) ? min(dist + 1, 200) : 0;
            sdn[i * 128 + j] = (unsigned short)dist;
        }
    } else {
        const int j = t - 128;
        int dist = 200;
        #pragma unroll 8
        for (int i = 127; i >= 0; --i) {
            dist = (mb[i * 128 + j] == label1) ? min(dist + 1, 200) : 0;
            sup[i * 128 + j] = (unsigned short)dist;
        }
    }
    __syncthreads();

    // ---- windowed row pass with fused combine:
    //      G2[jp] = min(sdn[jp],sup[jp])^2 computed at each probe.
    // Exact: after evaluating jp in [c0-e, c0+7+e], every unevaluated candidate
    // contributes >= (e+1)^2; stop once that can't beat any of the lane's 8 bests.
    const int row = rg * 16 + (t >> 4);
    const int c0  = (t & 15) * 8;
    const unsigned short* ga = &sdn[row * 128];
    const unsigned short* gb = &sup[row * 128];

    // initial window jp in [c0, c0+7]: two 16B LDS reads, dj^2 compile-time consts
    const uint4 va = *(const uint4*)(ga + c0);
    const uint4 vb = *(const uint4*)(gb + c0);
    int g[8];
    {
        const unsigned aw[4] = {va.x, va.y, va.z, va.w};
        const unsigned bw[4] = {vb.x, vb.y, vb.z, vb.w};
        #pragma unroll
        for (int q = 0; q < 4; ++q) {
            const int lo = min((int)(aw[q] & 0xffffu), (int)(bw[q] & 0xffffu));
            const int hi = min((int)(aw[q] >> 16),     (int)(bw[q] >> 16));
            g[2 * q]     = lo * lo;
            g[2 * q + 1] = hi * hi;
        }
    }

    int best[8];
    #pragma unroll
    for (int u = 0; u < 8; ++u) best[u] = 0x7fffffff;
    #pragma unroll
    for (int w = 0; w < 8; ++w) {
        #pragma unroll
        for (int u = 0; u < 8; ++u) {
            const int dj = u - w;                 // compile-time constant
            best[u] = min(best[u], g[w] + dj * dj);
        }
    }
    int mbst = 0;
    #pragma unroll
    for (int u = 0; u < 8; ++u) mbst = max(mbst, best[u]);

    // expand outward; wave-uniform trip count via __any vote
    for (int e = 0; e < 128; ++e) {
        if (!__any((e + 1) * (e + 1) < mbst)) break;
        const int jl = c0 - 1 - e;
        const int jr = c0 + 8 + e;
        if (jl >= 0) {
            const int ndl = min((int)ga[jl], (int)gb[jl]);
            const int gl  = ndl * ndl;
            #pragma unroll
            for (int u = 0; u < 8; ++u) {
                const int dj = u + 1 + e;         // (c0+u) - jl
                best[u] = min(best[u], gl + dj * dj);
            }
        }
        if (jr < 128) {
            const int ndr = min((int)ga[jr], (int)gb[jr]);
            const int gr  = ndr * ndr;
            #pragma unroll
            for (int u = 0; u < 8; ++u) {
                const int dj = 8 + e - u;         // jr - (c0+u)
                best[u] = min(best[u], gr + dj * dj);
            }
        }
        mbst = 0;
        #pragma unroll
        for (int u = 0; u < 8; ++u) mbst = max(mbst, best[u]);
    }

    // pack 8 u16 D2 values -> one 16B store (values <= 40000 fit u16)
    uint4 w;
    w.x = (unsigned)best[0] | ((unsigned)best[1] << 16);
    w.y = (unsigned)best[2] | ((unsigned)best[3] << 16);
    w.z = (unsigned)best[4] | ((unsigned)best[5] << 16);
    w.w = (unsigned)best[6] | ((unsigned)best[7] << 16);
    *(uint4*)(d2 + (b1 * KK + k1) * NPIX + row * 128 + c0) = w;

    // block max of D2 (mbst already = this lane's max over its 8 columns)
    int bm = mbst;
    #pragma unroll
    for (int off = 32; off; off >>= 1) bm = max(bm, __shfl_down(bm, off, 64));
    if ((t & 63) == 0) wmax[t >> 6] = bm;
    __syncthreads();
    if (t == 0)
        maxpart[bid] = max(max(wmax[0], wmax[1]), max(wmax[2], wmax[3]));
}

// Disjoint-support gt+loss: each pixel belongs to at most ONE instance, so gt has
// exactly one nonzero channel, selected by the pixel's own label.
// 256 blocks x 128 threads: one block per CU.
__global__ __launch_bounds__(128) void gt_loss_kernel(const float* __restrict__ pred,
                                                      const float* __restrict__ ign,
                                                      const int* __restrict__ mask,
                                                      const unsigned short* __restrict__ d2,
                                                      const int* __restrict__ maxpart,
                                                      float* __restrict__ out,
                                                      float* __restrict__ acc,
                                                      unsigned int* __restrict__ cnt) {
    __shared__ float msq[KK];
    __shared__ float wred[2];

    const int bid = blockIdx.x;           // 0..255
    const int t   = threadIdx.x;          // 0..127
    const int p   = bid * 128 + t;        // global pixel 0..32767
    const int b   = bid >> 7;             // 0..1  (all pixels of a block share b)
    const int pp  = p & (NPIX - 1);

    // msq[k] = sqrt(max D2) for this b (reduce the 8 row-group partials)
    if (t < KK) {
        const int base = b * 128 + t * 8;
        int mt = 0;
        #pragma unroll
        for (int r = 0; r < 8; ++r) mt = max(mt, maxpart[base + r]);
        msq[t] = __fsqrt_rn((float)mt);
    }
    __syncthreads();

    const int label = mask[p];
    int cbin = -1;                        // which gt channel is 1 (none if bg)
    if (label > 0) {
        const int k = label - 1;
        const float d  = __fsqrt_rn((float)d2[(b * KK + k) * NPIX + pp]);  // D2>=1
        float dn = __fdiv_rn(d, msq[k]);  // msq >= 1 since maxD2 >= D2 >= 1
        if (dn < 0.5f) dn = 0.0f;
        if (dn > 0.7f) dn = 1.0f;
        const float ddd[8] = {0.83f, 0.68f, 0.54f, 0.41f, 0.29f, 0.18f, 0.09f, 0.0f};
        #pragma unroll
        for (int c = 0; c < 8; ++c) {
            if (cbin < 0 && dn >= ddd[c]) cbin = c;
        }
    }

    float lsum = 0.0f;
    #pragma unroll
    for (int c = 0; c < 8; ++c) {
        const float g = (c == cbin) ? 1.0f : 0.0f;
        out[1 + (b * 8 + c) * NPIX + pp] = g;
        const float diff = pred[(b * 8 + c) * NPIX + pp] - g;
        const float ad = fabsf(diff);
        lsum += (ad < 1.0f) ? 0.5f * diff * diff : (ad - 0.5f);
    }
    float contrib = lsum * 0.125f * ign[p];

    #pragma unroll
    for (int off = 32; off; off >>= 1) contrib += __shfl_down(contrib, off, 64);
    if ((t & 63) == 0) wred[t >> 6] = contrib;
    __syncthreads();

    if (t == 0) {
        atomicAdd(acc, wred[0] + wred[1]);
        __threadfence();
        const unsigned int old = atomicAdd(cnt, 1u);
        if (old == 255u) {                        // last block: all adds visible
            const float total = atomicAdd(acc, 0.0f);
            out[0] = total * (1.0f / 32768.0f);
        }
    }
}

extern "C" void kernel_launch(void* const* d_in, const int* in_sizes, int n_in,
                              void* d_out, int out_size, void* d_ws, size_t ws_size,
                              hipStream_t stream) {
    const float* pred = (const float*)d_in[0];
    const int*   mask = (const int*)d_in[1];
    const float* ign  = (const float*)d_in[2];
    float* out = (float*)d_out;

    int*            maxpart = (int*)d_ws;
    float*          acc     = (float*)((char*)d_ws + 1024);
    unsigned int*   cnt     = (unsigned int*)((char*)d_ws + 1028);
    unsigned short* d2      = (unsigned short*)((char*)d_ws + 4096);

    edt_kernel<<<256, 256, 0, stream>>>(mask, maxpart, acc, cnt, d2);
    gt_loss_kernel<<<256, 128, 0, stream>>>(pred, ign, mask, d2, maxpart, out, acc, cnt);
}

// Round 5
// 70.142 us; speedup vs baseline: 1.7569x; 1.0564x over previous
//
#include <hip/hip_runtime.h>

#define KK 16
#define NPIX 16384   // 128*128

// ws layout (no zero-init required — K1 initializes acc/cnt, partials overwritten):
//   [0     .. 16383]  : int   maxpart[256*16]  per-row-block per-k D2 max,
//                              index = (b*128 + r)*16 + k
//   [16384 .. 16387]  : float acc   loss accumulator (K1 inits to 0)
//   [16388 .. 16391]  : uint  cnt   ticket counter   (K1 inits to 0)
//   [20480 .. +64KB]  : u16   d2own[32768]  squared dist to nearest differing label
//
// Key identity: gt at pixel p depends only on k = mask[p]-1 (bins are ANDed with
// nuclei), and max_k(d) is over instance-k pixels only. So the only EDT values
// ever consumed are D2_own[p] = min over q with mask[q] != mask[p] of |p-q|^2.
// One 64 KB field replaces 2x16 full EDT fields (16x less work, no k-gather).

__global__ __launch_bounds__(128) void edt_own_kernel(const int* __restrict__ mask,
                                                      int* __restrict__ maxpart,
                                                      float* __restrict__ acc,
                                                      unsigned int* __restrict__ cnt,
                                                      unsigned short* __restrict__ d2own) {
    __shared__ int lab[3][128];   // rows r-1, r, r+1 (255 = outside image)
    __shared__ int lmax[KK];

    const int bid = blockIdx.x;       // 0..255 = b*128 + r
    const int t   = threadIdx.x;      // 0..127 = column j
    const int b   = bid >> 7;
    const int r   = bid & 127;

    if (bid == 0 && t == 0) { *acc = 0.0f; *cnt = 0u; }  // init for K2
                                                         // (kernel boundary = visibility)
    if (t < KK) lmax[t] = 0;

    const int* mrow = mask + b * NPIX + r * 128;
    lab[1][t] = mrow[t];
    lab[0][t] = (r > 0)   ? mrow[t - 128] : 255;
    lab[2][t] = (r < 127) ? mrow[t + 128] : 255;
    __syncthreads();

    const int l = lab[1][t];
    int best;
    if (l == 0) {
        best = 0;                     // background pixel: EDT value never consumed
    } else {
        best = 0x7fffffff;
        // ---- ring 1: 8 neighbors from LDS (d2 = 1 or 2) ----
        const int lf = (t > 0)   ? lab[1][t - 1] : l;     // own-label sentinel = invalid
        const int rt = (t < 127) ? lab[1][t + 1] : l;
        if (lf != l) best = 1;
        if (rt != l) best = 1;
        const int up = lab[0][t];
        const int dn = lab[2][t];
        if (up != l && up != 255) best = min(best, 1);
        if (dn != l && dn != 255) best = min(best, 1);
        const int ul = (t > 0)   ? lab[0][t - 1] : 255;
        const int ur = (t < 127) ? lab[0][t + 1] : 255;
        const int dl = (t > 0)   ? lab[2][t - 1] : 255;
        const int dr = (t < 127) ? lab[2][t + 1] : 255;
        if (ul != l && ul != 255) best = min(best, 2);
        if (ur != l && ur != 255) best = min(best, 2);
        if (dl != l && dl != 255) best = min(best, 2);
        if (dr != l && dr != 255) best = min(best, 2);
    }

    // ---- expanding Chebyshev rings (exact; ~never executes on random labels) ----
    // After ring e-1, unexamined pixels have d2 >= e^2 -> continue iff e^2 < best.
    for (int e = 2; e < 128; ++e) {
        if (!__any(e * e < best)) break;
        if (e * e < best) {
            const int* mimg = mask + b * NPIX;
            for (int di = -e; di <= e; ++di) {
                const int rr = r + di;
                if (rr < 0 || rr > 127) continue;
                const int* rw = mimg + rr * 128;
                const int ad = (di < 0) ? -di : di;
                if (ad == e) {
                    const int j0 = max(t - e, 0), j1 = min(t + e, 127);
                    for (int jj = j0; jj <= j1; ++jj) {
                        if (rw[jj] != l) {
                            const int dj = jj - t;
                            best = min(best, di * di + dj * dj);
                        }
                    }
                } else {
                    const int jl = t - e, jr = t + e;
                    if (jl >= 0  && rw[jl] != l) best = min(best, di * di + e * e);
                    if (jr <= 127 && rw[jr] != l) best = min(best, di * di + e * e);
                }
            }
        }
    }

    best = min(best, 40000);          // uniform-image sentinel (matches 200^2); fits u16
    d2own[b * NPIX + r * 128 + t] = (unsigned short)best;

    if (l > 0) atomicMax(&lmax[l - 1], best);
    __syncthreads();
    if (t < KK) maxpart[bid * KK + t] = lmax[t];
}

// Disjoint-support gt+loss: each pixel belongs to at most ONE instance, so gt has
// exactly one nonzero channel, selected by the pixel's own label.
// 256 blocks x 128 threads; d2own read is now a coalesced stream (no k-gather).
__global__ __launch_bounds__(128) void gt_loss_kernel(const float* __restrict__ pred,
                                                      const float* __restrict__ ign,
                                                      const int* __restrict__ mask,
                                                      const unsigned short* __restrict__ d2own,
                                                      const int* __restrict__ maxpart,
                                                      float* __restrict__ out,
                                                      float* __restrict__ acc,
                                                      unsigned int* __restrict__ cnt) {
    __shared__ int   lmax2[KK];
    __shared__ float msq[KK];
    __shared__ float wred[2];

    const int bid = blockIdx.x;           // 0..255
    const int t   = threadIdx.x;          // 0..127
    const int p   = bid * 128 + t;        // global pixel 0..32767
    const int b   = bid >> 7;             // 0..1  (all pixels of a block share b)
    const int pp  = p & (NPIX - 1);

    // msq[k] = sqrt(max D2) for this b: reduce 128 row-block partials.
    // t -> (k = t&15, chunk c = t>>4): 8 threads/k x 16 rows each, LDS atomicMax.
    if (t < KK) lmax2[t] = 0;
    __syncthreads();
    {
        const int k = t & 15, c = t >> 4;
        const int* mp = maxpart + b * (128 * KK) + c * (16 * KK) + k;
        int pm = 0;
        #pragma unroll
        for (int rr = 0; rr < 16; ++rr) pm = max(pm, mp[rr * KK]);
        atomicMax(&lmax2[k], pm);
    }
    __syncthreads();
    if (t < KK) msq[t] = __fsqrt_rn((float)lmax2[t]);
    __syncthreads();

    const int label = mask[p];
    int cbin = -1;                        // which gt channel is 1 (none if bg)
    if (label > 0) {
        const float d  = __fsqrt_rn((float)d2own[p]);   // D2 >= 1 on instance pixels
        float dn = __fdiv_rn(d, msq[label - 1]);        // msq >= 1 since max >= 1
        if (dn < 0.5f) dn = 0.0f;
        if (dn > 0.7f) dn = 1.0f;
        const float ddd[8] = {0.83f, 0.68f, 0.54f, 0.41f, 0.29f, 0.18f, 0.09f, 0.0f};
        #pragma unroll
        for (int c = 0; c < 8; ++c) {
            if (cbin < 0 && dn >= ddd[c]) cbin = c;
        }
    }

    float lsum = 0.0f;
    #pragma unroll
    for (int c = 0; c < 8; ++c) {
        const float g = (c == cbin) ? 1.0f : 0.0f;
        out[1 + (b * 8 + c) * NPIX + pp] = g;
        const float diff = pred[(b * 8 + c) * NPIX + pp] - g;
        const float ad = fabsf(diff);
        lsum += (ad < 1.0f) ? 0.5f * diff * diff : (ad - 0.5f);
    }
    float contrib = lsum * 0.125f * ign[p];

    #pragma unroll
    for (int off = 32; off; off >>= 1) contrib += __shfl_down(contrib, off, 64);
    if ((t & 63) == 0) wred[t >> 6] = contrib;
    __syncthreads();

    if (t == 0) {
        atomicAdd(acc, wred[0] + wred[1]);
        __threadfence();
        const unsigned int old = atomicAdd(cnt, 1u);
        if (old == 255u) {                        // last block: all adds visible
            const float total = atomicAdd(acc, 0.0f);
            out[0] = total * (1.0f / 32768.0f);
        }
    }
}

extern "C" void kernel_launch(void* const* d_in, const int* in_sizes, int n_in,
                              void* d_out, int out_size, void* d_ws, size_t ws_size,
                              hipStream_t stream) {
    const float* pred = (const float*)d_in[0];
    const int*   mask = (const int*)d_in[1];
    const float* ign  = (const float*)d_in[2];
    float* out = (float*)d_out;

    int*            maxpart = (int*)d_ws;
    float*          acc     = (float*)((char*)d_ws + 16384);
    unsigned int*   cnt     = (unsigned int*)((char*)d_ws + 16388);
    unsigned short* d2own   = (unsigned short*)((char*)d_ws + 20480);

    edt_own_kernel<<<256, 128, 0, stream>>>(mask, maxpart, acc, cnt, d2own);
    gt_loss_kernel<<<256, 128, 0, stream>>>(pred, ign, mask, d2own, maxpart, out, acc, cnt);
}

// Round 6
// 65.281 us; speedup vs baseline: 1.8877x; 1.0745x over previous
//
#include <hip/hip_runtime.h>

#define KK 16
#define NPIX 16384   // 128*128

// ws layout (no zero-init required — K1 initializes acc/cnt, partials overwritten):
//   [0     .. 8191 ]  : int   maxpart[128*16]  per-2-row-block per-k D2 max,
//                              index = (b*64 + rb)*16 + k
//   [16384 .. 16387]  : float acc   loss accumulator (K1 inits to 0)
//   [16388 .. 16391]  : uint  cnt   ticket counter   (K1 inits to 0)
//   [20480 .. +64KB]  : u16   d2own[32768]  squared dist to nearest differing label
//
// Key identity: gt at pixel p depends only on k = mask[p]-1 (bins are ANDed with
// nuclei), and max_k(d) is over instance-k pixels only. So the only EDT values
// ever consumed are D2_own[p] = min over q with mask[q] != mask[p] of |p-q|^2.

__global__ __launch_bounds__(256) void edt_own_kernel(const int* __restrict__ mask,
                                                      int* __restrict__ maxpart,
                                                      float* __restrict__ acc,
                                                      unsigned int* __restrict__ cnt,
                                                      unsigned short* __restrict__ d2own) {
    __shared__ int lab[4][128];   // rows r0-1 .. r0+2 (255 = outside image)
    __shared__ int lmax[KK];

    const int bid = blockIdx.x;       // 0..127 = b*64 + rb
    const int t   = threadIdx.x;      // 0..255
    const int b   = bid >> 6;
    const int rb  = bid & 63;
    const int r0  = rb * 2;

    if (bid == 0 && t == 0) { *acc = 0.0f; *cnt = 0u; }  // init for K2
                                                         // (kernel boundary = visibility)
    if (t < KK) lmax[t] = 0;

    // stage 4 rows (each mask row loaded once per block)
    const int* mimg = mask + b * NPIX;
    #pragma unroll
    for (int s = t; s < 512; s += 256) {
        const int q = s >> 7, col = s & 127;
        const int rr = r0 - 1 + q;
        lab[q][col] = (rr >= 0 && rr <= 127) ? mimg[rr * 128 + col] : 255;
    }
    __syncthreads();

    const int h = t >> 7;             // which of the 2 rows this thread owns
    const int j = t & 127;            // column
    const int r = r0 + h;
    const int l = lab[h + 1][j];

    int best;
    if (l == 0) {
        best = 0;                     // background pixel: EDT value never consumed
    } else {
        best = 0x7fffffff;
        // ---- ring 1: 8 neighbors from LDS (d2 = 1 or 2) ----
        const int lf = (j > 0)   ? lab[h + 1][j - 1] : l;   // own-label = invalid
        const int rt = (j < 127) ? lab[h + 1][j + 1] : l;
        if (lf != l) best = 1;
        if (rt != l) best = 1;
        const int up = lab[h][j];
        const int dn = lab[h + 2][j];
        if (up != l && up != 255) best = min(best, 1);
        if (dn != l && dn != 255) best = min(best, 1);
        const int ul = (j > 0)   ? lab[h][j - 1]     : 255;
        const int ur = (j < 127) ? lab[h][j + 1]     : 255;
        const int dl = (j > 0)   ? lab[h + 2][j - 1] : 255;
        const int dr = (j < 127) ? lab[h + 2][j + 1] : 255;
        if (ul != l && ul != 255) best = min(best, 2);
        if (ur != l && ur != 255) best = min(best, 2);
        if (dl != l && dl != 255) best = min(best, 2);
        if (dr != l && dr != 255) best = min(best, 2);
    }

    // ---- expanding Chebyshev rings (exact; ~never executes on random labels) ----
    // After ring e-1, unexamined pixels have d2 >= e^2 -> continue iff e^2 < best.
    for (int e = 2; e < 128; ++e) {
        if (!__any(e * e < best)) break;
        if (e * e < best) {
            for (int di = -e; di <= e; ++di) {
                const int rr = r + di;
                if (rr < 0 || rr > 127) continue;
                const int* rw = mimg + rr * 128;
                const int ad = (di < 0) ? -di : di;
                if (ad == e) {
                    const int j0 = max(j - e, 0), j1 = min(j + e, 127);
                    for (int jj = j0; jj <= j1; ++jj) {
                        if (rw[jj] != l) {
                            const int dj = jj - j;
                            best = min(best, di * di + dj * dj);
                        }
                    }
                } else {
                    const int jl = j - e, jr = j + e;
                    if (jl >= 0   && rw[jl] != l) best = min(best, di * di + e * e);
                    if (jr <= 127 && rw[jr] != l) best = min(best, di * di + e * e);
                }
            }
        }
    }

    best = min(best, 40000);          // uniform-image sentinel (matches 200^2); fits u16
    d2own[b * NPIX + r * 128 + j] = (unsigned short)best;

    if (l > 0) atomicMax(&lmax[l - 1], best);
    __syncthreads();
    if (t < KK) maxpart[bid * KK + t] = lmax[t];
}

// Disjoint-support gt+loss: each pixel belongs to at most ONE instance, so gt has
// exactly one nonzero channel, selected by the pixel's own label.
// 128 blocks x 256 threads (256 pixels/block); d2own read is a coalesced stream.
__global__ __launch_bounds__(256) void gt_loss_kernel(const float* __restrict__ pred,
                                                      const float* __restrict__ ign,
                                                      const int* __restrict__ mask,
                                                      const unsigned short* __restrict__ d2own,
                                                      const int* __restrict__ maxpart,
                                                      float* __restrict__ out,
                                                      float* __restrict__ acc,
                                                      unsigned int* __restrict__ cnt) {
    __shared__ int   lmax2[KK];
    __shared__ float msq[KK];
    __shared__ float wred[4];

    const int bid = blockIdx.x;           // 0..127
    const int t   = threadIdx.x;          // 0..255
    const int p   = bid * 256 + t;        // global pixel 0..32767
    const int b   = bid >> 6;             // 0..1  (all pixels of a block share b)
    const int pp  = p & (NPIX - 1);

    // msq[k] = sqrt(max D2) for this b: reduce 64 row-block partials.
    // threads t<64 -> (k = t&15, chunk c = t>>4): 4 threads/k x 16 row-blocks each.
    if (t < KK) lmax2[t] = 0;
    __syncthreads();
    if (t < 64) {
        const int k = t & 15, c = t >> 4;
        const int* mp = maxpart + b * (64 * KK) + c * (16 * KK) + k;
        int pm = 0;
        #pragma unroll
        for (int rr = 0; rr < 16; ++rr) pm = max(pm, mp[rr * KK]);
        atomicMax(&lmax2[k], pm);
    }
    __syncthreads();
    if (t < KK) msq[t] = __fsqrt_rn((float)lmax2[t]);
    __syncthreads();

    const int label = mask[p];
    int cbin = -1;                        // which gt channel is 1 (none if bg)
    if (label > 0) {
        const float d  = __fsqrt_rn((float)d2own[p]);   // D2 >= 1 on instance pixels
        float dn = __fdiv_rn(d, msq[label - 1]);        // msq >= 1 since max >= 1
        if (dn < 0.5f) dn = 0.0f;
        if (dn > 0.7f) dn = 1.0f;
        const float ddd[8] = {0.83f, 0.68f, 0.54f, 0.41f, 0.29f, 0.18f, 0.09f, 0.0f};
        #pragma unroll
        for (int c = 0; c < 8; ++c) {
            if (cbin < 0 && dn >= ddd[c]) cbin = c;
        }
    }

    float lsum = 0.0f;
    #pragma unroll
    for (int c = 0; c < 8; ++c) {
        const float g = (c == cbin) ? 1.0f : 0.0f;
        out[1 + (b * 8 + c) * NPIX + pp] = g;
        const float diff = pred[(b * 8 + c) * NPIX + pp] - g;
        const float ad = fabsf(diff);
        lsum += (ad < 1.0f) ? 0.5f * diff * diff : (ad - 0.5f);
    }
    float contrib = lsum * 0.125f * ign[p];

    #pragma unroll
    for (int off = 32; off; off >>= 1) contrib += __shfl_down(contrib, off, 64);
    if ((t & 63) == 0) wred[t >> 6] = contrib;
    __syncthreads();

    if (t == 0) {
        atomicAdd(acc, (wred[0] + wred[1]) + (wred[2] + wred[3]));
        __threadfence();
        const unsigned int old = atomicAdd(cnt, 1u);
        if (old == 127u) {                        // last block: all adds visible
            const float total = atomicAdd(acc, 0.0f);
            out[0] = total * (1.0f / 32768.0f);
        }
    }
}

extern "C" void kernel_launch(void* const* d_in, const int* in_sizes, int n_in,
                              void* d_out, int out_size, void* d_ws, size_t ws_size,
                              hipStream_t stream) {
    const float* pred = (const float*)d_in[0];
    const int*   mask = (const int*)d_in[1];
    const float* ign  = (const float*)d_in[2];
    float* out = (float*)d_out;

    int*            maxpart = (int*)d_ws;
    float*          acc     = (float*)((char*)d_ws + 16384);
    unsigned int*   cnt     = (unsigned int*)((char*)d_ws + 16388);
    unsigned short* d2own   = (unsigned short*)((char*)d_ws + 20480);

    edt_own_kernel<<<128, 256, 0, stream>>>(mask, maxpart, acc, cnt, d2own);
    gt_loss_kernel<<<128, 256, 0, stream>>>(pred, ign, mask, d2own, maxpart, out, acc, cnt);
}